// Round 1
// baseline (328.515 us; speedup 1.0000x reference)
//
#include <hip/hip_runtime.h>

// ---------------- problem constants ----------------
// x:[N,128] W1:[128,128] b1:[128] W2:[128,64] b2:[64] edge_index:[2,E]
// out:[N,64] fp32. Intermediates bf16; GEMMs use bf16 MFMA (fp32 accum).

static constexpr int BSHIFT = 7;          // 128 node ids per coarse bucket
static constexpr int BWIDTH = 1 << BSHIFT;
static constexpr int MAXBUCK = 2048;      // supports N <= 262144 (pack needs N < 2^20)
static constexpr int NPART = 256;         // partition/hist grid size

// ---------------- workspace layout (bytes) ----------------
static constexpr size_t OFF_FLAG = 0;         // u32[1]
static constexpr size_t OFF_DEG  = 256;       // u32[N]
static constexpr size_t OFF_ROW  = 458752;    // u32[N+1]
static constexpr size_t OFF_BSUM = 917504;    // u32[1024]
static constexpr size_t OFF_CCNT = 925696;    // u32[MAXBUCK+1]
static constexpr size_t OFF_COFF = 937984;    // u32[MAXBUCK+1]
static constexpr size_t OFF_DINV = 962560;    // f32[N]
static constexpr size_t OFF_CSR  = 1376256;   // i32[E]            (6.4 MB)
static constexpr size_t OFF_HS1  = 8388608;   // bf16[N*128] 25.6 MB; aliases part u32[E]
static constexpr size_t OFF_OUT1 = 35651584;  // bf16[N*128] 25.6 MB
static constexpr size_t OFF_HS2  = 62914560;  // bf16[N*64]  12.8 MB (ends 75714560)
static constexpr size_t OFF_H2   = 75714560;  // u32[MAXBUCK*NPART] (800 KB used)

// ---------------- bf16 helpers ----------------
__device__ __forceinline__ unsigned short f2bf(float f) {  // RNE
    unsigned u = __float_as_uint(f);
    u += 0x7fffu + ((u >> 16) & 1u);
    return (unsigned short)(u >> 16);
}

typedef __attribute__((ext_vector_type(8))) short bf16x8;
typedef __attribute__((ext_vector_type(4))) float f32x4;
typedef __attribute__((ext_vector_type(4))) unsigned u32x4;

// ---------------- edge dtype detection (+ ccnt zeroing, fused) -----------
__global__ void detect_kernel(const unsigned* __restrict__ w,
                              unsigned* __restrict__ flag,
                              unsigned* __restrict__ ccnt, int nbuck) {
    int i = blockIdx.x * blockDim.x + threadIdx.x;   // 4096 threads
    if (i <= nbuck) ccnt[i] = 0;
    if (w[2 * i + 1] != 0u) atomicOr(flag, 1u);
}

__device__ __forceinline__ int edge_dst(const unsigned* w, unsigned flag,
                                        int e, int E) {
    return flag ? (int)w[E + e] : (int)w[2 * E + 2 * e];
}
__device__ __forceinline__ int edge_src(const unsigned* w, unsigned flag,
                                        int e, int E) {
    return flag ? (int)w[e] : (int)w[2 * e];
}

// ---------------- pass A: coarse histogram (stores per-block hist) ---------
__global__ __launch_bounds__(1024) void coarse_hist_kernel(
    const unsigned* __restrict__ w, const unsigned* __restrict__ flag,
    unsigned* __restrict__ ccnt, unsigned* __restrict__ h2, int E, int nbuck) {
    __shared__ unsigned hist[MAXBUCK];
    for (int i = threadIdx.x; i < nbuck; i += 1024) hist[i] = 0;
    __syncthreads();
    const unsigned f = *flag;
    const int per = (E + gridDim.x - 1) / gridDim.x;
    const int e0 = blockIdx.x * per, e1 = min(E, e0 + per);
    for (int e = e0 + (int)threadIdx.x; e < e1; e += 1024)
        atomicAdd(&hist[edge_dst(w, f, e, E) >> BSHIFT], 1u);
    __syncthreads();
    for (int i = threadIdx.x; i < nbuck; i += 1024) {
        unsigned h = hist[i];
        h2[(size_t)i * NPART + blockIdx.x] = h;
        if (h) atomicAdd(&ccnt[i], h);
    }
}

// ---------------- coarse scan: coff = exclusive_scan(ccnt) ----------------
__global__ __launch_bounds__(1024) void coarse_scan_kernel(
    const unsigned* __restrict__ ccnt, unsigned* __restrict__ coff, int nbuck) {
    __shared__ unsigned sh[1024];
    const int t = threadIdx.x;
    unsigned run = 0;
    for (int b0 = 0; b0 < nbuck; b0 += 1024) {
        unsigned v = (b0 + t < nbuck) ? ccnt[b0 + t] : 0u;
        sh[t] = v;
        __syncthreads();
        for (int off = 1; off < 1024; off <<= 1) {
            unsigned a = (t >= off) ? sh[t - off] : 0u;
            __syncthreads();
            sh[t] += a;
            __syncthreads();
        }
        if (b0 + t < nbuck) coff[b0 + t] = run + sh[t] - v;
        run += sh[1023];
        __syncthreads();
    }
    if (t == 0) coff[nbuck] = run;   // == E
}

// ---------------- off2d: h2[b][blk] -> per-block write cursor --------------
__global__ __launch_bounds__(NPART) void off2d_kernel(
    unsigned* __restrict__ h2, const unsigned* __restrict__ coff) {
    __shared__ unsigned sh[NPART];
    const int b = blockIdx.x, t = threadIdx.x;
    unsigned v = h2[(size_t)b * NPART + t];
    sh[t] = v;
    __syncthreads();
#pragma unroll
    for (int off = 1; off < NPART; off <<= 1) {
        unsigned a = (t >= off) ? sh[t - off] : 0u;
        __syncthreads();
        sh[t] += a;
        __syncthreads();
    }
    h2[(size_t)b * NPART + t] = coff[b] + sh[t] - v;   // exclusive + base
}

// ---------------- pass B: partition (packed 4 B entries) ----------------
// part entry = src | (dst&127)<<20  (valid: N < 2^20)
__global__ __launch_bounds__(1024) void partition_kernel(
    const unsigned* __restrict__ w, const unsigned* __restrict__ flag,
    const unsigned* __restrict__ h2, unsigned* __restrict__ part, int E,
    int nbuck) {
    __shared__ unsigned lcur[MAXBUCK];
    for (int i = threadIdx.x; i < nbuck; i += 1024)
        lcur[i] = h2[(size_t)i * NPART + blockIdx.x];
    __syncthreads();
    const unsigned f = *flag;
    const int per = (E + gridDim.x - 1) / gridDim.x;
    const int e0 = blockIdx.x * per, e1 = min(E, e0 + per);
    for (int e = e0 + (int)threadIdx.x; e < e1; e += 1024) {
        int d = edge_dst(w, f, e, E);
        int s = edge_src(w, f, e, E);
        unsigned pos = atomicAdd(&lcur[d >> BSHIFT], 1u);
        part[pos] = (unsigned)s | ((unsigned)(d & (BWIDTH - 1)) << 20);
    }
}

// ---------------- pass C: per-bucket deg + local scan + CSR write ----------
__global__ __launch_bounds__(256) void bucket_csr_kernel(
    const unsigned* __restrict__ part, const unsigned* __restrict__ coff,
    unsigned* __restrict__ deg, int* __restrict__ csr, int N) {
    __shared__ unsigned cnt[BWIDTH];
    __shared__ unsigned sc[BWIDTH];
    __shared__ unsigned cur[BWIDTH];
    const int b = blockIdx.x, base = b << BSHIFT, t = threadIdx.x;
    if (t < BWIDTH) cnt[t] = 0;
    __syncthreads();
    const int e0 = (int)coff[b], e1 = (int)coff[b + 1];
    for (int e = e0 + t; e < e1; e += 256)
        atomicAdd(&cnt[part[e] >> 20], 1u);
    __syncthreads();
    if (t < BWIDTH && base + t < N) deg[base + t] = cnt[t];
    if (t < BWIDTH) sc[t] = cnt[t];
    __syncthreads();
#pragma unroll
    for (int off = 1; off < BWIDTH; off <<= 1) {
        unsigned a = (t < BWIDTH && t >= off) ? sc[t - off] : 0u;
        __syncthreads();
        if (t < BWIDTH) sc[t] += a;
        __syncthreads();
    }
    if (t < BWIDTH) cur[t] = (unsigned)e0 + sc[t] - cnt[t];
    __syncthreads();
    for (int e = e0 + t; e < e1; e += 256) {
        unsigned pk = part[e];
        unsigned p = atomicAdd(&cur[pk >> 20], 1u);
        csr[p] = (int)(pk & 0xFFFFFu);
    }
}

// ---------------- scans over deg -> row; dinv ----------------
__global__ __launch_bounds__(1024) void scan1_kernel(
    const unsigned* __restrict__ deg, unsigned* __restrict__ row,
    unsigned* __restrict__ bsum, int N) {
    __shared__ unsigned sh[1024];
    int gid = blockIdx.x * 1024 + threadIdx.x;
    int t = threadIdx.x;
    unsigned v = (gid < N) ? deg[gid] : 0u;
    sh[t] = v;
    __syncthreads();
#pragma unroll
    for (int off = 1; off < 1024; off <<= 1) {
        unsigned add = (t >= off) ? sh[t - off] : 0u;
        __syncthreads();
        sh[t] += add;
        __syncthreads();
    }
    if (gid < N) row[gid + 1] = sh[t];
    if (t == 1023) bsum[blockIdx.x] = sh[1023];
}

__global__ __launch_bounds__(1024) void scan2_kernel(unsigned* __restrict__ bsum,
                                                     int NB) {
    __shared__ unsigned sh[1024];
    const int t = threadIdx.x;
    unsigned v = (t < NB) ? bsum[t] : 0u;
    sh[t] = v;
    __syncthreads();
#pragma unroll
    for (int off = 1; off < 1024; off <<= 1) {
        unsigned a = (t >= off) ? sh[t - off] : 0u;
        __syncthreads();
        sh[t] += a;
        __syncthreads();
    }
    if (t < NB) bsum[t] = sh[t] - v;
}

__global__ void scan3_kernel(unsigned* __restrict__ row,
                             const unsigned* __restrict__ bsum,
                             const unsigned* __restrict__ deg,
                             float* __restrict__ dinv, int N) {
    int gid = blockIdx.x * blockDim.x + threadIdx.x;
    if (gid >= N) return;
    row[gid + 1] += bsum[gid >> 10];
    if (gid == 0) row[0] = 0u;
    dinv[gid] = rsqrtf((float)deg[gid] + 1.0f);
}

// ---------------- MFMA GEMM: out_bf16 = (A @ B) * dinv[row] ----------------
// 128xBN tile, K=128 single shot, 16x16x32 bf16 MFMA.
// LDS holds A and B pre-swizzled into fragment order:
//   frag(m-tile mt, kstep ks) element offset = ((mt*4+ks)*16 + m)*4 + q)*8 + j
//   lane L reads 8 contiguous bf16 at m=L&15, q=L>>4  -> one ds_read_b128.
// Layouts (m89-verified): A[m=lane&15][k=q*8+j]; B[k=q*8+j][n=lane&15];
// D row=q*4+reg, col=lane&15.
template <int BN, bool ABF16>
__global__ __launch_bounds__(256) void gemm_mfma(
    const void* __restrict__ Av, const float* __restrict__ B,
    const float* __restrict__ dinv, unsigned short* __restrict__ out, int M) {
    constexpr int NT = BN / 16;          // col tiles (8 or 4)
    __shared__ short sA[16384];          // 8 rowtiles * 4 ks * 512  (32 KB)
    __shared__ short sB[NT * 2048];      // NT ntiles  * 4 ks * 512  (32/16 KB)

    const int t = threadIdx.x;
    const int row0 = blockIdx.x * 128;
    const int w = t >> 6, lane = t & 63;
    const int m = lane & 15, q = lane >> 4;

    // ---- stage A (fp32 or bf16 -> swizzled bf16) ----
    if (ABF16) {
        const unsigned short* A = (const unsigned short*)Av;
        for (int g = t; g < 2048; g += 256) {     // 128*128/8
            int r = g >> 4, k0 = (g & 15) << 3;
            uint4 v = make_uint4(0u, 0u, 0u, 0u);
            if (row0 + r < M) v = *(const uint4*)(A + (size_t)(row0 + r) * 128 + k0);
            int off = ((((r >> 4) * 4 + (k0 >> 5)) * 16 + (r & 15)) * 4 +
                       ((k0 >> 3) & 3)) * 8;
            *(uint4*)(sA + off) = v;
        }
    } else {
        const float* A = (const float*)Av;
        for (int g = t; g < 4096; g += 256) {     // 128*128/4
            int r = g >> 5, k0 = (g & 31) << 2;
            float4 v = make_float4(0.f, 0.f, 0.f, 0.f);
            if (row0 + r < M) v = *(const float4*)(A + (size_t)(row0 + r) * 128 + k0);
            ushort4 u;
            u.x = f2bf(v.x); u.y = f2bf(v.y); u.z = f2bf(v.z); u.w = f2bf(v.w);
            int off = ((((r >> 4) * 4 + (k0 >> 5)) * 16 + (r & 15)) * 4 +
                       ((k0 >> 3) & 3)) * 8 + (k0 & 4);
            *(ushort4*)(sA + off) = u;
        }
    }
    // ---- stage B (fp32 [128][BN] -> swizzled bf16) ----
    for (int g = t; g < BN * 32; g += 256) {
        int n = g % BN, k0 = (g / BN) * 4;        // lanes: consecutive n -> coalesced
        float f0 = B[(size_t)(k0 + 0) * BN + n];
        float f1 = B[(size_t)(k0 + 1) * BN + n];
        float f2 = B[(size_t)(k0 + 2) * BN + n];
        float f3 = B[(size_t)(k0 + 3) * BN + n];
        ushort4 u;
        u.x = f2bf(f0); u.y = f2bf(f1); u.z = f2bf(f2); u.w = f2bf(f3);
        int off = ((((n >> 4) * 4 + (k0 >> 5)) * 16 + (n & 15)) * 4 +
                   ((k0 >> 3) & 3)) * 8 + (k0 & 4);
        *(ushort4*)(sB + off) = u;
    }
    __syncthreads();

    f32x4 acc[2][NT];
#pragma unroll
    for (int lt = 0; lt < 2; lt++)
#pragma unroll
        for (int nt = 0; nt < NT; nt++) acc[lt][nt] = (f32x4){0.f, 0.f, 0.f, 0.f};

    const int fb = (m * 4 + q) * 8;   // lane's frag offset within a 512-el group
#pragma unroll
    for (int ks = 0; ks < 4; ks++) {
        bf16x8 a0 = *(const bf16x8*)(sA + ((w * 2 + 0) * 4 + ks) * 512 + fb);
        bf16x8 a1 = *(const bf16x8*)(sA + ((w * 2 + 1) * 4 + ks) * 512 + fb);
#pragma unroll
        for (int nt = 0; nt < NT; nt++) {
            bf16x8 b = *(const bf16x8*)(sB + (nt * 4 + ks) * 512 + fb);
            acc[0][nt] = __builtin_amdgcn_mfma_f32_16x16x32_bf16(a0, b, acc[0][nt], 0, 0, 0);
            acc[1][nt] = __builtin_amdgcn_mfma_f32_16x16x32_bf16(a1, b, acc[1][nt], 0, 0, 0);
        }
    }

    // ---- epilogue: scale by dinv, store bf16 ----
#pragma unroll
    for (int lt = 0; lt < 2; lt++) {
#pragma unroll
        for (int r = 0; r < 4; r++) {
            int row = row0 + w * 32 + lt * 16 + q * 4 + r;
            if (row < M) {
                float s = dinv[row];
#pragma unroll
                for (int nt = 0; nt < NT; nt++)
                    out[(size_t)row * BN + nt * 16 + m] = f2bf(acc[lt][nt][r] * s);
            }
        }
    }
}

// ---------------- gather aggregation + fused epilogue (bf16 table) ---------
// out[i] = maybe_relu( dinv[i] * ( hs[i] + sum_{e in row i} hs[csr[e]] ) + b )
// Lane owns 8 channels (uint4 = 16 B of bf16). LPN = C/8 lanes per node.
// Latency-bound gather: double-buffer the csr index batch and issue gathers
// 8-deep into registers before consuming (keeps ~8 loads in flight per lane).
#define ACC8(u)                                                                \
    do {                                                                       \
        s0 += __uint_as_float((u).x << 16);                                    \
        s1 += __uint_as_float((u).x & 0xffff0000u);                            \
        s2 += __uint_as_float((u).y << 16);                                    \
        s3 += __uint_as_float((u).y & 0xffff0000u);                            \
        s4 += __uint_as_float((u).z << 16);                                    \
        s5 += __uint_as_float((u).z & 0xffff0000u);                            \
        s6 += __uint_as_float((u).w << 16);                                    \
        s7 += __uint_as_float((u).w & 0xffff0000u);                            \
    } while (0)

template <int C, bool RELU, bool OUTBF>
__global__ __launch_bounds__(256) void agg_kernel(
    const int* __restrict__ csr, const unsigned* __restrict__ row,
    const unsigned short* __restrict__ hsb, const float* __restrict__ dinv,
    const float* __restrict__ bias, void* __restrict__ outv, int N) {
    constexpr int LPN = C / 8;  // lanes per node (16 or 8)
    const int tid = blockIdx.x * 256 + threadIdx.x;
    const int i = tid / LPN;
    const int l = tid % LPN;
    if (i >= N) return;

    const int co = 8 * l;
    const unsigned short* __restrict__ tab = hsb + co;
    float s0 = 0.f, s1 = 0.f, s2 = 0.f, s3 = 0.f,
          s4 = 0.f, s5 = 0.f, s6 = 0.f, s7 = 0.f;
    {
        uint4 u = *(const uint4*)(tab + (size_t)i * C);   // self
        ACC8(u);
    }

    const int rs = (int)row[i], re = (int)row[i + 1];
    int e = rs;
    int idx = (rs + l < re) ? csr[rs + l] : 0;            // first batch
    while (e < re) {
        const int cnt = min(LPN, re - e);
        const int idx_c = idx;
        e += LPN;
        idx = (e + l < re) ? csr[e + l] : 0;              // prefetch next batch
        if (cnt == LPN) {
#pragma unroll
            for (int h = 0; h < LPN / 8; ++h) {
                uint4 v[8];
#pragma unroll
                for (int j = 0; j < 8; ++j) {
                    const int s = __shfl(idx_c, h * 8 + j, LPN);
                    v[j] = *(const uint4*)(tab + (size_t)s * C);
                }
#pragma unroll
                for (int j = 0; j < 8; ++j) ACC8(v[j]);
            }
        } else {
            for (int j = 0; j < cnt; ++j) {
                const int s = __shfl(idx_c, j, LPN);
                uint4 v = *(const uint4*)(tab + (size_t)s * C);
                ACC8(v);
            }
        }
    }

    const float sc = dinv[i];
    const float4 ba = *(const float4*)(bias + co);
    const float4 bb = *(const float4*)(bias + co + 4);
    float o0 = s0 * sc + ba.x, o1 = s1 * sc + ba.y;
    float o2 = s2 * sc + ba.z, o3 = s3 * sc + ba.w;
    float o4 = s4 * sc + bb.x, o5 = s5 * sc + bb.y;
    float o6 = s6 * sc + bb.z, o7 = s7 * sc + bb.w;
    if (RELU) {
        o0 = fmaxf(o0, 0.f); o1 = fmaxf(o1, 0.f); o2 = fmaxf(o2, 0.f);
        o3 = fmaxf(o3, 0.f); o4 = fmaxf(o4, 0.f); o5 = fmaxf(o5, 0.f);
        o6 = fmaxf(o6, 0.f); o7 = fmaxf(o7, 0.f);
    }
    if (OUTBF) {
        u32x4 u;
        u.x = (unsigned)f2bf(o0) | ((unsigned)f2bf(o1) << 16);
        u.y = (unsigned)f2bf(o2) | ((unsigned)f2bf(o3) << 16);
        u.z = (unsigned)f2bf(o4) | ((unsigned)f2bf(o5) << 16);
        u.w = (unsigned)f2bf(o6) | ((unsigned)f2bf(o7) << 16);
        // NT store: don't evict the gather table from L2 for a write stream
        __builtin_nontemporal_store(
            u, (u32x4*)((unsigned short*)outv + (size_t)i * C + co));
    } else {
        f32x4 a = (f32x4){o0, o1, o2, o3};
        f32x4 b = (f32x4){o4, o5, o6, o7};
        float* op = (float*)outv + (size_t)i * C + co;
        __builtin_nontemporal_store(a, (f32x4*)op);
        __builtin_nontemporal_store(b, (f32x4*)(op + 4));
    }
}

// ---------------- launch ----------------
extern "C" void kernel_launch(void* const* d_in, const int* in_sizes, int n_in,
                              void* d_out, int out_size, void* d_ws,
                              size_t ws_size, hipStream_t stream) {
    const float* x  = (const float*)d_in[0];
    const float* W1 = (const float*)d_in[1];
    const float* b1 = (const float*)d_in[2];
    const float* W2 = (const float*)d_in[3];
    const float* b2 = (const float*)d_in[4];
    const unsigned* ew = (const unsigned*)d_in[5];
    const int E = in_sizes[5] / 2;        // 1,600,000
    const int N = in_sizes[0] / 128;      // 100,000
    const int NB = (N + 1023) >> 10;
    const int nbuck = (N + BWIDTH - 1) >> BSHIFT;   // 782

    char* ws = (char*)d_ws;
    unsigned* flag = (unsigned*)(ws + OFF_FLAG);
    unsigned* deg  = (unsigned*)(ws + OFF_DEG);
    unsigned* row  = (unsigned*)(ws + OFF_ROW);
    unsigned* bsum = (unsigned*)(ws + OFF_BSUM);
    unsigned* ccnt = (unsigned*)(ws + OFF_CCNT);
    unsigned* coff = (unsigned*)(ws + OFF_COFF);
    float* dinv    = (float*)(ws + OFF_DINV);
    int* csr       = (int*)(ws + OFF_CSR);
    unsigned short* hs1  = (unsigned short*)(ws + OFF_HS1);
    unsigned short* out1 = (unsigned short*)(ws + OFF_OUT1);
    unsigned short* hs2  = (unsigned short*)(ws + OFF_HS2);
    unsigned* h2   = (unsigned*)(ws + OFF_H2);
    unsigned* part = (unsigned*)(ws + OFF_HS1);  // dead before gemm1 writes hs1

    hipMemsetAsync(flag, 0, 4, stream);

    // ---- CSR build ----
    detect_kernel<<<16, 256, 0, stream>>>(ew, flag, ccnt, nbuck);
    coarse_hist_kernel<<<NPART, 1024, 0, stream>>>(ew, flag, ccnt, h2, E, nbuck);
    coarse_scan_kernel<<<1, 1024, 0, stream>>>(ccnt, coff, nbuck);
    off2d_kernel<<<nbuck, NPART, 0, stream>>>(h2, coff);
    partition_kernel<<<NPART, 1024, 0, stream>>>(ew, flag, h2, part, E, nbuck);
    bucket_csr_kernel<<<nbuck, 256, 0, stream>>>(part, coff, deg, csr, N);
    scan1_kernel<<<NB, 1024, 0, stream>>>(deg, row, bsum, N);
    scan2_kernel<<<1, 1024, 0, stream>>>(bsum, NB);
    scan3_kernel<<<(N + 255) / 256, 256, 0, stream>>>(row, bsum, deg, dinv, N);

    // ---- layer 1 (C=128) ----
    gemm_mfma<128, false><<<(N + 127) / 128, 256, 0, stream>>>(x, W1, dinv, hs1, N);
    agg_kernel<128, true, true><<<(N * 16 + 255) / 256, 256, 0, stream>>>(
        csr, row, hs1, dinv, b1, out1, N);

    // ---- layer 2 (C=64) ----
    gemm_mfma<64, true><<<(N + 127) / 128, 256, 0, stream>>>(out1, W2, dinv, hs2, N);
    agg_kernel<64, false, false><<<(N * 8 + 255) / 256, 256, 0, stream>>>(
        csr, row, hs2, dinv, b2, d_out, N);
}